// Round 6
// baseline (28.603 us; speedup 1.0000x reference)
//
#include <hip/hip_runtime.h>

// SvmLoss N=8192, RANK_RATIO=1.0 -> out = rank_loss (scalar f32).
// rank_loss = sum_{i,j} [t_i<t_j && status_i==1] * max(1+logit_j-logit_i,0)^2
//             / max(#pairs,1)
//
// R6: SINGLE dispatch. R5's packed branch-free loop + hierarchical
// last-block-done tail using AGENT-scope __hip_atomic_* (cache-bypassing, no
// heavyweight __threadfence L2-writeback; atomics spread over 32 group
// counters -> no same-address serialization, which cost R3 ~20us).
// Counter reset eliminated: last = ((old+1) & 31)==0 fires exactly once per
// 32 increments for ANY starting value (poison/replay/garbage-proof, output
// value-invariant -> deterministic).

typedef float f32x2 __attribute__((ext_vector_type(2)));

constexpr int N_   = 8192;
constexpr int BLK  = 256;
constexpr int R    = 4;               // j columns per lane
constexpr int JPB  = BLK * R;         // 1024 j per block
constexpr int NJB  = N_ / JPB;        // 8 j-blocks
constexpr int ICH  = 64;              // i per chunk
constexpr int NIC  = N_ / ICH;        // 128 i-chunks
constexpr int GRID = NJB * NIC;       // 1024 blocks = 4/CU
constexpr int GSZ  = 32;              // blocks per counter group
constexpr int NGRP = GRID / GSZ;      // 32 groups

__global__ __launch_bounds__(BLK) void svm_onepass(
        const float* __restrict__ logit,
        const float* __restrict__ st,             // [N][2] status,time
        unsigned long long* __restrict__ pair,    // [GRID]  (cnt<<32 | f32bits)
        unsigned long long* __restrict__ gpair,   // [NGRP]
        unsigned int* __restrict__ gcnt,          // [NGRP]
        unsigned int* __restrict__ fcnt,          // [1]
        float* __restrict__ out) {
    __shared__ float2 ci_s[ICH];                  // (logit_i, t_eff_i)
    __shared__ float  wsum[BLK / 64];
    __shared__ int    wcnt[BLK / 64];
    __shared__ bool   lastg_s, lastf_s;

    const int jb = blockIdx.x & (NJB - 1);
    const int ic = blockIdx.x / NJB;
    const int g  = blockIdx.x / GSZ;
    const int j0 = jb * JPB + (int)threadIdx.x * R;    // 16B-aligned

    const float4 lj4 = *(const float4*)(logit + j0);
    const float4 sa  = *(const float4*)(st + 2 * j0);      // (s,t) j0,j0+1
    const float4 sb  = *(const float4*)(st + 2 * j0 + 4);  // (s,t) j0+2,j0+3
    // x = li - (1+lj); hinge^2 = min(x,0)^2
    const f32x2 nljpA = { -(1.0f + lj4.x), -(1.0f + lj4.y) };
    const f32x2 nljpB = { -(1.0f + lj4.z), -(1.0f + lj4.w) };
    const float tj0 = sa.y, tj1 = sa.w, tj2 = sb.y, tj3 = sb.w;

    const int i0 = ic * ICH;
    if (threadIdx.x < ICH) {
        const int    i  = i0 + (int)threadIdx.x;
        const float  li = logit[i];
        const float2 sv = *(const float2*)(st + 2 * i);
        const float  te = (sv.x == 1.0f) ? sv.y : 1e30f;   // status gate
        ci_s[threadIdx.x] = make_float2(li, te);
    }
    __syncthreads();

    f32x2 sA = {0.f, 0.f}, sB = {0.f, 0.f};
    int cnt = 0;                                   // wave-uniform -> SGPR
    #pragma unroll 8
    for (int k = 0; k < ICH; ++k) {
        const float2 ct = ci_s[k];                 // ds_read_b64 broadcast
        const float  li = ct.x, te = ct.y;
        const f32x2  li2 = { li, li };
        f32x2 xA = li2 + nljpA;                    // v_pk_add_f32
        f32x2 xB = li2 + nljpB;
        float h0 = fminf(xA.x, 0.f);               // -hinge
        float h1 = fminf(xA.y, 0.f);
        float h2 = fminf(xB.x, 0.f);
        float h3 = fminf(xB.y, 0.f);
        const bool m0 = te < tj0;
        const bool m1 = te < tj1;
        const bool m2 = te < tj2;
        const bool m3 = te < tj3;
        f32x2 hmA = { m0 ? h0 : 0.f, m1 ? h1 : 0.f };
        f32x2 hmB = { m2 ? h2 : 0.f, m3 ? h3 : 0.f };
        sA += hmA * hmA;                           // v_pk_fma_f32
        sB += hmB * hmB;
        cnt += (int)__popcll(__ballot(m0));        // SALU pipe
        cnt += (int)__popcll(__ballot(m1));
        cnt += (int)__popcll(__ballot(m2));
        cnt += (int)__popcll(__ballot(m3));
    }

    float sum = (sA.x + sA.y) + (sB.x + sB.y);
    for (int off = 32; off > 0; off >>= 1)
        sum += __shfl_down(sum, off, 64);

    const int lane = threadIdx.x & 63;
    const int wid  = threadIdx.x >> 6;
    if (lane == 0) { wsum[wid] = sum; wcnt[wid] = cnt; }
    __syncthreads();
    if (threadIdx.x == 0) {
        const float s = (wsum[0] + wsum[1]) + (wsum[2] + wsum[3]);
        const int   c =  wcnt[0] + wcnt[1] + wcnt[2] + wcnt[3];
        const unsigned long long p =
            ((unsigned long long)(unsigned int)c << 32) |
             (unsigned long long)__float_as_uint(s);
        __hip_atomic_store(&pair[blockIdx.x], p,
                           __ATOMIC_RELAXED, __HIP_MEMORY_SCOPE_AGENT);
        // release (waitcnt-only) orders the store before the counter bump
        const unsigned int old = __hip_atomic_fetch_add(
            &gcnt[g], 1u, __ATOMIC_ACQ_REL, __HIP_MEMORY_SCOPE_AGENT);
        lastg_s = ((old + 1u) & (GSZ - 1u)) == 0u;   // any start value works
    }
    __syncthreads();
    if (!lastg_s) return;

    // ---- group reduce (one block per group of 32): wave 0 only ----
    {
        float s = 0.f; int c = 0;
        if (threadIdx.x < GSZ) {
            const unsigned long long p = __hip_atomic_load(
                &pair[g * GSZ + threadIdx.x],
                __ATOMIC_RELAXED, __HIP_MEMORY_SCOPE_AGENT);
            s = __uint_as_float((unsigned int)p);
            c = (int)(unsigned int)(p >> 32);
        }
        if (threadIdx.x < 64) {
            for (int off = 16; off > 0; off >>= 1) {
                s += __shfl_down(s, off, 64);
                c += __shfl_down(c, off, 64);
            }
            if (threadIdx.x == 0) {
                const unsigned long long p =
                    ((unsigned long long)(unsigned int)c << 32) |
                     (unsigned long long)__float_as_uint(s);
                __hip_atomic_store(&gpair[g], p,
                                   __ATOMIC_RELAXED, __HIP_MEMORY_SCOPE_AGENT);
                const unsigned int old2 = __hip_atomic_fetch_add(
                    fcnt, 1u, __ATOMIC_ACQ_REL, __HIP_MEMORY_SCOPE_AGENT);
                lastf_s = ((old2 + 1u) & (NGRP - 1u)) == 0u;
            }
        }
    }
    __syncthreads();
    if (!lastf_s) return;

    // ---- final reduce (exactly one block): wave 0 only ----
    {
        float s = 0.f; int c = 0;
        if (threadIdx.x < NGRP) {
            const unsigned long long p = __hip_atomic_load(
                &gpair[threadIdx.x],
                __ATOMIC_RELAXED, __HIP_MEMORY_SCOPE_AGENT);
            s = __uint_as_float((unsigned int)p);
            c = (int)(unsigned int)(p >> 32);
        }
        if (threadIdx.x < 64) {
            for (int off = 16; off > 0; off >>= 1) {
                s += __shfl_down(s, off, 64);
                c += __shfl_down(c, off, 64);
            }
            if (threadIdx.x == 0)
                out[0] = s / (float)(c > 0 ? c : 1);
        }
    }
}

extern "C" void kernel_launch(void* const* d_in, const int* in_sizes, int n_in,
                              void* d_out, int out_size, void* d_ws, size_t ws_size,
                              hipStream_t stream) {
    const float* logit = (const float*)d_in[0];   // (N,1) f32
    const float* st    = (const float*)d_in[1];   // (N,2) f32

    unsigned long long* pair  = (unsigned long long*)d_ws;               // [1024]
    unsigned long long* gpair = (unsigned long long*)((char*)d_ws + 8192);  // [32]
    unsigned int*       gcnt  = (unsigned int*)((char*)d_ws + 8448);     // [32]
    unsigned int*       fcnt  = (unsigned int*)((char*)d_ws + 8576);     // [1]

    svm_onepass<<<GRID, BLK, 0, stream>>>(logit, st, pair, gpair, gcnt, fcnt,
                                          (float*)d_out);
}

// Round 7
// 16.628 us; speedup vs baseline: 1.7202x; 1.7202x over previous
//
#include <hip/hip_runtime.h>

// SvmLoss N=8192, RANK_RATIO=1.0 -> out = rank_loss (scalar f32).
// rank_loss = sum_{i,j} [t_i<t_j && status_i==1] * max(1+logit_j-logit_i,0)^2
//             / max(#pairs,1)
//
// R7: two-kernel structure (R4/R6 established: fused atomic tails cost
// +10..20us). New:
//  (a) wave-ballot COMPACTION of status-1 i-rows per 64-chunk (one wave does
//      ballot+prefix-popc -> compacted LDS), halving inner-loop trips;
//  (b) count via per-lane v_addc (cnt += mask, reusing the vcc from the
//      cndmask compare) instead of 4x ballot+popc on the shared SALU pipe.
// Packed f32 hinge math retained: hinge^2 = min(li-(1+lj),0)^2.

typedef float f32x2 __attribute__((ext_vector_type(2)));

constexpr int N_   = 8192;
constexpr int BLK  = 256;
constexpr int R    = 4;               // j columns per lane
constexpr int JPB  = BLK * R;         // 1024 j per block
constexpr int NJB  = N_ / JPB;        // 8 j-blocks
constexpr int ICH  = 64;              // i per chunk (= one wave for compaction)
constexpr int NIC  = N_ / ICH;        // 128 i-chunks
constexpr int GRID = NJB * NIC;       // 1024 blocks = 4/CU

__global__ __launch_bounds__(BLK) void svm_partial(
        const float* __restrict__ logit,
        const float* __restrict__ st,      // [N][2] status,time
        float* __restrict__ psum,
        int*   __restrict__ pcnt) {
    __shared__ float2 ci_s[ICH];          // compacted (logit_i, time_i), status==1
    __shared__ int    total_s;

    const int jb = blockIdx.x & (NJB - 1);
    const int ic = blockIdx.x / NJB;
    const int j0 = jb * JPB + (int)threadIdx.x * R;   // 16B-aligned

    const float4 lj4 = *(const float4*)(logit + j0);
    const float4 sa  = *(const float4*)(st + 2 * j0);      // (s,t) j0,j0+1
    const float4 sb  = *(const float4*)(st + 2 * j0 + 4);  // (s,t) j0+2,j0+3
    // x = li - (1+lj); hinge^2 = min(x,0)^2
    const f32x2 nljpA = { -(1.0f + lj4.x), -(1.0f + lj4.y) };
    const f32x2 nljpB = { -(1.0f + lj4.z), -(1.0f + lj4.w) };
    const float tj0 = sa.y, tj1 = sa.w, tj2 = sb.y, tj3 = sb.w;

    // Wave 0 compacts the chunk's status-1 rows into LDS (deterministic order)
    if (threadIdx.x < 64) {
        const int    i    = ic * ICH + (int)threadIdx.x;
        const float  li   = logit[i];
        const float2 sv   = *(const float2*)(st + 2 * i);
        const bool   keep = (sv.x == 1.0f);
        const unsigned long long mk = __ballot(keep);
        const int pos = (int)__popcll(mk & ((1ull << threadIdx.x) - 1ull));
        if (keep) ci_s[pos] = make_float2(li, sv.y);
        if (threadIdx.x == 0) total_s = (int)__popcll(mk);
    }
    __syncthreads();
    const int total = total_s;            // wave-uniform loop bound

    f32x2 sA = {0.f, 0.f}, sB = {0.f, 0.f};
    int c0 = 0, c1 = 0, c2 = 0, c3 = 0;   // per-lane counts (v_addc, no SALU)
    #pragma unroll 4
    for (int k = 0; k < total; ++k) {
        const float2 ct = ci_s[k];        // ds_read_b64 broadcast
        const float  li = ct.x, te = ct.y;
        const f32x2  li2 = { li, li };
        f32x2 xA = li2 + nljpA;           // v_pk_add_f32
        f32x2 xB = li2 + nljpB;
        float h0 = fminf(xA.x, 0.f);      // -hinge
        float h1 = fminf(xA.y, 0.f);
        float h2 = fminf(xB.x, 0.f);
        float h3 = fminf(xB.y, 0.f);
        const bool m0 = te < tj0;
        const bool m1 = te < tj1;
        const bool m2 = te < tj2;
        const bool m3 = te < tj3;
        f32x2 hmA = { m0 ? h0 : 0.f, m1 ? h1 : 0.f };
        f32x2 hmB = { m2 ? h2 : 0.f, m3 ? h3 : 0.f };
        sA += hmA * hmA;                  // v_pk_fma_f32
        sB += hmB * hmB;
        c0 += (int)m0;                    // v_addc_co_u32 (reuses vcc)
        c1 += (int)m1;
        c2 += (int)m2;
        c3 += (int)m3;
    }

    float sum = (sA.x + sA.y) + (sB.x + sB.y);
    int   cnt = (c0 + c1) + (c2 + c3);
    for (int off = 32; off > 0; off >>= 1) {
        sum += __shfl_down(sum, off, 64);
        cnt += __shfl_down(cnt, off, 64);
    }

    __shared__ float wsum[BLK / 64];
    __shared__ int   wcnt[BLK / 64];
    const int lane = threadIdx.x & 63;
    const int wid  = threadIdx.x >> 6;
    if (lane == 0) { wsum[wid] = sum; wcnt[wid] = cnt; }
    __syncthreads();
    if (threadIdx.x == 0) {
        psum[blockIdx.x] = (wsum[0] + wsum[1]) + (wsum[2] + wsum[3]);
        pcnt[blockIdx.x] =  wcnt[0] + wcnt[1] + wcnt[2] + wcnt[3];
    }
}

__global__ __launch_bounds__(BLK) void svm_final(
        const float* __restrict__ psum,
        const int* __restrict__ pcnt,
        float* __restrict__ out) {
    float s = 0.f;
    int   c = 0;
    for (int t = (int)threadIdx.x; t < GRID; t += BLK) {   // fixed order
        s += psum[t];
        c += pcnt[t];
    }
    for (int off = 32; off > 0; off >>= 1) {
        s += __shfl_down(s, off, 64);
        c += __shfl_down(c, off, 64);
    }
    __shared__ float wsum[BLK / 64];
    __shared__ int   wcnt[BLK / 64];
    const int lane = threadIdx.x & 63;
    const int wid  = threadIdx.x >> 6;
    if (lane == 0) { wsum[wid] = s; wcnt[wid] = c; }
    __syncthreads();
    if (threadIdx.x == 0) {
        const float S = (wsum[0] + wsum[1]) + (wsum[2] + wsum[3]);
        const int   C =  wcnt[0] + wcnt[1] + wcnt[2] + wcnt[3];
        out[0] = S / (float)(C > 0 ? C : 1);
    }
}

extern "C" void kernel_launch(void* const* d_in, const int* in_sizes, int n_in,
                              void* d_out, int out_size, void* d_ws, size_t ws_size,
                              hipStream_t stream) {
    const float* logit = (const float*)d_in[0];   // (N,1) f32
    const float* st    = (const float*)d_in[1];   // (N,2) f32

    float* psum = (float*)d_ws;                      // [GRID]
    int*   pcnt = (int*)((char*)d_ws + GRID * 4);    // [GRID]

    svm_partial<<<GRID, BLK, 0, stream>>>(logit, st, psum, pcnt);
    svm_final<<<1, BLK, 0, stream>>>(psum, pcnt, (float*)d_out);
}